// Round 13
// baseline (432.796 us; speedup 1.0000x reference)
//
#include <hip/hip_runtime.h>
#include <hip/hip_fp16.h>
#include <math.h>

// ---------------------------------------------------------------------------
// GCN autoencoder: 4 layers (12->16->8->16->12), N=200K nodes, E=5M edges.
//
// Round 13 (on R12's 408 us):
//  * final_kernel fused into layer-4 gather (sigmoid+bias epilogue writes
//    out directly) -> one fewer kernel + 9.6 MB round trip.
//  * bin: chunk 6144->4096 (EPT 8, ~23 KB LDS) -> 1221 blocks, ~4 blocks/CU.
//  * gather: unroll x4 quads (16 table loads in flight per lane).
// Gather is vmem-request-rate bound (~0.31 req/cyc/CU measured ~= the
// concurrency*latency ceiling); traffic is near compulsory (79 MB).
// ---------------------------------------------------------------------------

#define NPB 1024               // nodes per bucket; bucket id = dst >> 10
#define MAX_NB 256             // supports N <= 262144
#define CAP 26496              // bucket region capacity (mean 25510 + ~6s)
#define BIN_CHUNK 4096         // edges per workgroup in bin_kernel
#define BIN_TH 512             // threads per workgroup in bin_kernel
#define EPT (BIN_CHUNK / BIN_TH)  // edges per thread (8)
#define MAXB CAP               // LDS col staging capacity (full bucket)

__global__ void init_cur_kernel(int* __restrict__ bucket_cur, int NB) {
    int t = blockIdx.x * blockDim.x + threadIdx.x;
    if (t < NB) bucket_cur[t] = t * CAP;
}

// Block-level LDS counting sort of a 4096-edge chunk (512 threads):
//   LDS hist -> block scan -> reserve global runs (1 atomic/bucket, regions
//   are fixed-capacity) -> LDS scatter (records + bucket-id bytes) ->
//   coalesced flush with O(1) bucket lookup. Records: (src<<10)|local_dst.
__global__ __launch_bounds__(BIN_TH) void bin_kernel(const int* __restrict__ src,
                                                     const int* __restrict__ dst,
                                                     int* __restrict__ bucket_cur,
                                                     unsigned int* __restrict__ binned,
                                                     int E, int NB) {
    __shared__ int h[MAX_NB];          // hist, then reused as scatter cursor
    __shared__ int scl[MAX_NB + 1];    // block-local exclusive offsets
    __shared__ int base[MAX_NB];       // global run bases
    __shared__ int sscan[256];
    __shared__ unsigned int stage[BIN_CHUNK];   // 16 KB
    __shared__ unsigned char bkt8[BIN_CHUNK];   // 4 KB bucket ids
    int cbeg = blockIdx.x * BIN_CHUNK;
    int cend = min(cbeg + BIN_CHUNK, E);
    int chunk_n = cend - cbeg;
    int tid = threadIdx.x;

    for (int t = tid; t < NB; t += BIN_TH) h[t] = 0;
    __syncthreads();
    int myd[EPT];
#pragma unroll
    for (int j = 0; j < EPT; j++) {
        int e = cbeg + tid + j * BIN_TH;
        if (e < cend) {
            myd[j] = dst[e];
            atomicAdd(&h[myd[j] >> 10], 1);
        }
    }
    __syncthreads();
    // exclusive scan of h[0..NB) using the first 256 threads (NB <= 256);
    // ALL threads execute the same barrier sequence.
    int v = (tid < NB) ? h[tid] : 0;
    if (tid < 256) sscan[tid] = v;
    __syncthreads();
    for (int off = 1; off < 256; off <<= 1) {
        int t = (tid >= off && tid < 256) ? sscan[tid - off] : 0;
        __syncthreads();
        if (tid < 256) sscan[tid] += t;
        __syncthreads();
    }
    if (tid < NB) {
        scl[tid] = sscan[tid] - v;
        base[tid] = v ? atomicAdd(&bucket_cur[tid], v) : 0;
    }
    if (tid == 0) scl[NB] = chunk_n;
    __syncthreads();
    for (int t = tid; t < NB; t += BIN_TH) h[t] = 0;  // reuse as cursor
    __syncthreads();
#pragma unroll
    for (int j = 0; j < EPT; j++) {
        int e = cbeg + tid + j * BIN_TH;
        if (e < cend) {
            int d = myd[j];
            int bkt = d >> 10;
            int pos = scl[bkt] + atomicAdd(&h[bkt], 1);
            stage[pos] = ((unsigned)src[e] << 10) | (unsigned)(d & 1023);
            bkt8[pos] = (unsigned char)bkt;
        }
    }
    __syncthreads();
    // coalesced flush: O(1) bucket lookup via bkt8
    for (int k = tid; k < chunk_n; k += BIN_TH) {
        int bkt = bkt8[k];
        binned[base[bkt] + (k - scl[bkt])] = stage[k];
    }
}

// One WG per FULL bucket (1024 nodes, 1024 threads): per-node count + scan
// in LDS, emit rows(int2)/dis, scatter src into LDS colbuf, flush coalesced.
__global__ __launch_bounds__(1024) void csr_bucket_kernel(
    const unsigned int* __restrict__ binned,
    const int* __restrict__ bucket_cur,
    int2* __restrict__ rows, float* __restrict__ dis,
    int* __restrict__ col, int N) {
    __shared__ int cnt[NPB];
    __shared__ int cur[NPB];
    __shared__ int colbuf[MAXB];   // 104 KB
    int b = blockIdx.x;
    int nbase = b << 10;
    int nlocal = min(NPB, N - nbase);
    int beg = b * CAP;
    int bsize = bucket_cur[b] - beg;
    int tid = threadIdx.x;

    cnt[tid] = 0;
    __syncthreads();
    for (int k = tid; k < bsize; k += 1024)
        atomicAdd(&cnt[binned[beg + k] & 1023u], 1);
    __syncthreads();
    int v = cnt[tid];
    cur[tid] = v;
    __syncthreads();
    for (int off = 1; off < 1024; off <<= 1) {
        int t = (tid >= off) ? cur[tid - off] : 0;
        __syncthreads();
        cur[tid] += t;
        __syncthreads();
    }
    int excl = cur[tid] - v;
    if (tid < nlocal) {
        rows[nbase + tid] = make_int2(beg + excl, beg + excl + v);
        dis[nbase + tid] = 1.0f / sqrtf((float)(v + 1));  // +1 self-loop
    }
    __syncthreads();
    cur[tid] = excl;
    __syncthreads();
    if (bsize <= MAXB) {
        for (int k = tid; k < bsize; k += 1024) {
            unsigned rec = binned[beg + k];
            int pos = atomicAdd(&cur[rec & 1023u], 1);
            colbuf[pos] = (int)(rec >> 10);
        }
        __syncthreads();
        for (int k = tid; k < bsize; k += 1024) col[beg + k] = colbuf[k];
    } else {  // cannot trigger with CAP sizing; correctness fallback
        for (int k = tid; k < bsize; k += 1024) {
            unsigned rec = binned[beg + k];
            int pos = atomicAdd(&cur[rec & 1023u], 1);
            col[beg + pos] = (int)(rec >> 10);
        }
    }
}

// PREACT: 0 = raw input (layer 1), 1 = bias + relu, 2 = bias only.
// SPLITIN: input from two chunk arrays of IN/2 each (SoA agg).
template <int IN, int OUT, int C, int PREACT, bool SPLITIN>
__global__ __launch_bounds__(256) void transform_kernel(
    const float* __restrict__ hin0, const float* __restrict__ hin1,
    const float* __restrict__ bias_prev,
    const float* __restrict__ W, const float* __restrict__ dis,
    __half* __restrict__ xls, int N) {
    __shared__ float sW[IN * OUT];
    __shared__ float sB[IN];
    for (int t = threadIdx.x; t < IN * OUT; t += blockDim.x) sW[t] = W[t];
    if (PREACT != 0) {
        for (int t = threadIdx.x; t < IN; t += blockDim.x) sB[t] = bias_prev[t];
    }
    __syncthreads();
    int i = blockIdx.x * blockDim.x + threadIdx.x;
    if (i >= N) return;

    constexpr int CIN = SPLITIN ? IN / 2 : IN;
    float h[IN];
#pragma unroll
    for (int k = 0; k < IN; k++) {
        float v;
        if (SPLITIN)
            v = (k < CIN) ? hin0[(size_t)i * CIN + k]
                          : hin1[(size_t)i * CIN + (k - CIN)];
        else
            v = hin0[(size_t)i * IN + k];
        if (PREACT != 0) {
            v += sB[k];
            if (PREACT == 1) v = fmaxf(v, 0.0f);
        }
        h[k] = v;
    }
    float d = dis[i];
    float o[OUT];
#pragma unroll
    for (int f = 0; f < OUT; f++) {
        float acc = 0.0f;
#pragma unroll
        for (int k = 0; k < IN; k++) acc = fmaf(h[k], sW[k * OUT + f], acc);
        o[f] = acc * d;  // pre-scaled by dis[i]
    }
    constexpr int NCH = OUT / C;
    constexpr int P = C / 2;
    __half2* x2 = (__half2*)xls;
#pragma unroll
    for (int c = 0; c < NCH; c++) {
#pragma unroll
        for (int k = 0; k < P; k++) {
            x2[(size_t)c * N * P + (size_t)i * P + k] =
                __floats2half2_rn(o[c * C + 2 * k], o[c * C + 2 * k + 1]);
        }
    }
}

// Accumulate one source node's C features into acc.
template <int P>
__device__ __forceinline__ void acc_node(const __half2* __restrict__ x2, int c,
                                         float2 (&acc)[P]) {
    __half2 t[P];
#pragma unroll
    for (int k = 0; k < P; k++) t[k] = x2[(size_t)c * P + k];
#pragma unroll
    for (int k = 0; k < P; k++) {
        float2 v = __half22float2(t[k]);
        acc[k].x += v.x;
        acc[k].y += v.y;
    }
}

template <int P>
__device__ __forceinline__ void acc_quad(const __half2* __restrict__ x2, int4 c,
                                         float2 (&acc)[P]) {
    __half2 t[4][P];
#pragma unroll
    for (int k = 0; k < P; k++) t[0][k] = x2[(size_t)c.x * P + k];
#pragma unroll
    for (int k = 0; k < P; k++) t[1][k] = x2[(size_t)c.y * P + k];
#pragma unroll
    for (int k = 0; k < P; k++) t[2][k] = x2[(size_t)c.z * P + k];
#pragma unroll
    for (int k = 0; k < P; k++) t[3][k] = x2[(size_t)c.w * P + k];
#pragma unroll
    for (int k = 0; k < P; k++) {
        float2 a0 = __half22float2(t[0][k]), a1 = __half22float2(t[1][k]);
        float2 a2 = __half22float2(t[2][k]), a3 = __half22float2(t[3][k]);
        acc[k].x += (a0.x + a1.x) + (a2.x + a3.x);
        acc[k].y += (a0.y + a1.y) + (a2.y + a3.y);
    }
}

// Pull gather body: lane-pair per node, 16B-aligned int4 col quads, lane p
// handles quads p, p+2, ..., unrolled x4 (16 table loads in flight).
// Epilogue: SIG=false -> store acc*d to outp (contiguous, stride OST=C);
//           SIG=true  -> store sigmoid(acc*d + bias[coff+f]) (stride OST).
template <int C, bool SIG, int OST>
__device__ __forceinline__ void gather_body(
    int i, int p, const int2* __restrict__ rows, const int* __restrict__ col,
    const float* __restrict__ dis, const __half2* __restrict__ x2,
    float* __restrict__ outp, const float* __restrict__ bias, int coff) {
    constexpr int P = C / 2;
    float2 acc[P];
#pragma unroll
    for (int k = 0; k < P; k++) {
        if (p == 0) acc[k] = __half22float2(x2[(size_t)i * P + k]);  // self-loop
        else acc[k] = make_float2(0.0f, 0.0f);
    }
    int2 r = rows[i];
    int beg = r.x;
    int end = r.y;
    int nedge = end - beg;
    // scalar prologue to 16B alignment (lane p takes alternating edges)
    int pre = (4 - (beg & 3)) & 3;
    if (pre > nedge) pre = nedge;
    for (int j = p; j < pre; j += 2) acc_node<P>(x2, col[beg + j], acc);
    int abeg = beg + pre;
    int nq = (end - abeg) >> 2;  // full aligned quads
    int q = p;
    // unroll x4: four quads (16 edges / 16 table loads) in flight per lane
    for (; q + 6 < nq; q += 8) {
        int4 ca = *reinterpret_cast<const int4*>(col + abeg + 4 * q);
        int4 cb = *reinterpret_cast<const int4*>(col + abeg + 4 * (q + 2));
        int4 cc = *reinterpret_cast<const int4*>(col + abeg + 4 * (q + 4));
        int4 cd = *reinterpret_cast<const int4*>(col + abeg + 4 * (q + 6));
        acc_quad<P>(x2, ca, acc);
        acc_quad<P>(x2, cb, acc);
        acc_quad<P>(x2, cc, acc);
        acc_quad<P>(x2, cd, acc);
    }
    for (; q < nq; q += 2) {  // leftover quads for this lane (up to 3)
        int4 ca = *reinterpret_cast<const int4*>(col + abeg + 4 * q);
        acc_quad<P>(x2, ca, acc);
    }
    // scalar tail (lane p takes alternating edges)
    int tbeg = abeg + 4 * nq;
    for (int j = tbeg + p; j < end; j += 2) acc_node<P>(x2, col[j], acc);
    // combine pair partials (both lanes end with the full sum)
#pragma unroll
    for (int k = 0; k < P; k++) {
        acc[k].x += __shfl_xor(acc[k].x, 1);
        acc[k].y += __shfl_xor(acc[k].y, 1);
    }
    float d = dis[i];
    float* op = outp + (size_t)i * OST + coff;
#pragma unroll
    for (int k = 0; k < P; k++) {
        if ((k & 1) == p) {
            float vx = acc[k].x * d;
            float vy = acc[k].y * d;
            if (SIG) {
                vx = 1.0f / (1.0f + expf(-(vx + bias[coff + 2 * k])));
                vy = 1.0f / (1.0f + expf(-(vy + bias[coff + 2 * k + 1])));
            }
            *reinterpret_cast<float2*>(op + 2 * k) = make_float2(vx, vy);
        }
    }
}

// Single-chunk gather (layer 2).
template <int C>
__global__ __launch_bounds__(256) void gather_kernel(
    const int2* __restrict__ rows, const int* __restrict__ col,
    const float* __restrict__ dis, const __half* __restrict__ xls,
    float* __restrict__ aggc, int N) {
    int tid = blockIdx.x * blockDim.x + threadIdx.x;
    int i = tid >> 1;
    int p = tid & 1;
    if (i >= N) return;
    gather_body<C, false, C>(i, p, rows, col, dis, (const __half2*)xls, aggc,
                             nullptr, 0);
}

// Merged two-chunk gather: chunk = (blockIdx&7)>=4. With round-robin
// block->XCD dispatch each XCD's L2 caches only one 3.2 MB chunk table;
// coverage (and thus correctness) does not depend on the mapping.
template <int C>
__global__ __launch_bounds__(256) void gather2_kernel(
    const int2* __restrict__ rows, const int* __restrict__ col,
    const float* __restrict__ dis, const __half* __restrict__ x0,
    const __half* __restrict__ x1, float* __restrict__ agg0,
    float* __restrict__ agg1, int N) {
    int grp = blockIdx.x >> 3;
    int sub = blockIdx.x & 7;
    int chunk = sub >> 2;
    int range = (grp << 2) + (sub & 3);
    int t2 = range * 256 + (int)threadIdx.x;
    int i = t2 >> 1;
    int p = t2 & 1;
    if (i >= N) return;
    const __half2* x2 = (const __half2*)(chunk ? x1 : x0);
    float* aggc = chunk ? agg1 : agg0;
    gather_body<C, false, C>(i, p, rows, col, dis, x2, aggc, nullptr, 0);
}

// Layer-4 merged gather with fused bias+sigmoid epilogue -> out (stride 12).
__global__ __launch_bounds__(256) void gather2_sig_kernel(
    const int2* __restrict__ rows, const int* __restrict__ col,
    const float* __restrict__ dis, const __half* __restrict__ x0,
    const __half* __restrict__ x1, const float* __restrict__ bias,
    float* __restrict__ out, int N) {
    int grp = blockIdx.x >> 3;
    int sub = blockIdx.x & 7;
    int chunk = sub >> 2;
    int range = (grp << 2) + (sub & 3);
    int t2 = range * 256 + (int)threadIdx.x;
    int i = t2 >> 1;
    int p = t2 & 1;
    if (i >= N) return;
    const __half2* x2 = (const __half2*)(chunk ? x1 : x0);
    gather_body<6, true, 12>(i, p, rows, col, dis, x2, out, bias, chunk ? 6 : 0);
}

static inline size_t align_up(size_t v, size_t a) { return (v + a - 1) & ~(a - 1); }

extern "C" void kernel_launch(void* const* d_in, const int* in_sizes, int n_in,
                              void* d_out, int out_size, void* d_ws, size_t ws_size,
                              hipStream_t stream) {
    const float* x  = (const float*)d_in[0];
    const int*   ei = (const int*)d_in[1];
    const float* W1 = (const float*)d_in[2];
    const float* b1 = (const float*)d_in[3];
    const float* W2 = (const float*)d_in[4];
    const float* b2 = (const float*)d_in[5];
    const float* W3 = (const float*)d_in[6];
    const float* b3 = (const float*)d_in[7];
    const float* W4 = (const float*)d_in[8];
    const float* b4 = (const float*)d_in[9];
    float* out = (float*)d_out;

    const int N = in_sizes[0] / 12;
    const int E = in_sizes[1] / 2;
    const int* src = ei;       // edge_index[0]
    const int* dst = ei + E;   // edge_index[1]
    const int NB = (N + NPB - 1) / NPB;  // 196

    // Workspace carve-up (~77 MB)
    char* ws = (char*)d_ws;
    size_t off = 0;
    int* bucket_cur = (int*)(ws + off);   off = align_up(off + (size_t)NB * 4, 256);
    int2* rows = (int2*)(ws + off);       off = align_up(off + (size_t)N * 8, 256);
    float* dis = (float*)(ws + off);      off = align_up(off + (size_t)N * 4, 256);
    unsigned int* binned = (unsigned int*)(ws + off);
    off = align_up(off + ((size_t)NB * CAP + 4096) * 4, 256);
    int* col = (int*)(ws + off);          off = align_up(off + ((size_t)NB * CAP + 4096) * 4, 256);
    __half* xls = (__half*)(ws + off);    off = align_up(off + (size_t)N * 16 * 2, 256);
    float* aggA = (float*)(ws + off);     off = align_up(off + (size_t)N * 16 * 4, 256);
    float* aggB = (float*)(ws + off);     off = align_up(off + (size_t)N * 16 * 4, 256);
    (void)ws_size; (void)n_in; (void)out_size;

    const int B = 256;
    auto blocks = [&](long long n) { return (int)((n + B - 1) / B); };
    int nb2 = blocks(2LL * N);          // ranges for merged gather
    nb2 = (nb2 + 3) & ~3;               // multiple of 4
    const int G2 = nb2 * 2;             // merged-gather grid (mult of 8)

    // --- CSR build: fixed-capacity bucketed counting sort ----------------
    init_cur_kernel<<<1, 256, 0, stream>>>(bucket_cur, NB);
    bin_kernel<<<(E + BIN_CHUNK - 1) / BIN_CHUNK, BIN_TH, 0, stream>>>(src, dst, bucket_cur, binned, E, NB);
    csr_bucket_kernel<<<NB, 1024, 0, stream>>>(binned, bucket_cur, rows, dis, col, N);

    // xls chunk-table bases (half units): chunk c of size C lives at c*N*C
    __half* x_c0 = xls;
    __half* x_c8 = xls + (size_t)N * 8;  // second chunk for C=8 layers
    __half* x_c6 = xls + (size_t)N * 6;  // second chunk for C=6 layer
    // SoA agg chunk bases
    float* aggA0 = aggA;
    float* aggA1 = aggA + (size_t)N * 8;
    float* aggB0 = aggB;

    // --- Layer 1: x(12) @ W1 -> 16 (chunks 2x8, merged gather) -----------
    transform_kernel<12, 16, 8, 0, false><<<blocks(N), B, 0, stream>>>(
        x, nullptr, nullptr, W1, dis, xls, N);
    gather2_kernel<8><<<G2, B, 0, stream>>>(rows, col, dis, x_c0, x_c8, aggA0, aggA1, N);

    // --- Layer 2: relu(aggA + b1)(16) @ W2 -> 8 (1x8) --------------------
    transform_kernel<16, 8, 8, 1, true><<<blocks(N), B, 0, stream>>>(
        aggA0, aggA1, b1, W2, dis, xls, N);
    gather_kernel<8><<<blocks(2LL * N), B, 0, stream>>>(rows, col, dis, x_c0, aggB0, N);

    // --- Layer 3: (aggB + b2)(8) @ W3 -> 16 (2x8 merged, no relu) --------
    transform_kernel<8, 16, 8, 2, false><<<blocks(N), B, 0, stream>>>(
        aggB0, nullptr, b2, W3, dis, xls, N);
    gather2_kernel<8><<<G2, B, 0, stream>>>(rows, col, dis, x_c0, x_c8, aggA0, aggA1, N);

    // --- Layer 4: relu(aggA + b3)(16) @ W4 -> 12 (2x6 merged,
    //     fused bias+sigmoid epilogue straight to out) --------------------
    transform_kernel<16, 12, 6, 1, true><<<blocks(N), B, 0, stream>>>(
        aggA0, aggA1, b3, W4, dis, xls, N);
    gather2_sig_kernel<<<G2, B, 0, stream>>>(rows, col, dis, x_c0, x_c6, b4, out, N);
}

// Round 14
// 408.543 us; speedup vs baseline: 1.0594x; 1.0594x over previous
//
#include <hip/hip_runtime.h>
#include <hip/hip_fp16.h>
#include <math.h>

// ---------------------------------------------------------------------------
// GCN autoencoder: 4 layers (12->16->8->16->12), N=200K nodes, E=5M edges.
//
// Round 14: R13's unroll x4 regressed (compiler dropped VGPR 60->40 and
// re-serialized loads; occupancy 35->49% diluted per-XCD L2 table reuse,
// FETCH 79->113 MB). Revert gather to R12's exact unroll x3; KEEP R13's
// fused bias+sigmoid layer-4 epilogue and BIN_CHUNK=4096.
// Sweet spot: moderate occupancy (~35%) x high per-lane MLP (12 loads).
// ---------------------------------------------------------------------------

#define NPB 1024               // nodes per bucket; bucket id = dst >> 10
#define MAX_NB 256             // supports N <= 262144
#define CAP 26496              // bucket region capacity (mean 25510 + ~6s)
#define BIN_CHUNK 4096         // edges per workgroup in bin_kernel
#define BIN_TH 512             // threads per workgroup in bin_kernel
#define EPT (BIN_CHUNK / BIN_TH)  // edges per thread (8)
#define MAXB CAP               // LDS col staging capacity (full bucket)

__global__ void init_cur_kernel(int* __restrict__ bucket_cur, int NB) {
    int t = blockIdx.x * blockDim.x + threadIdx.x;
    if (t < NB) bucket_cur[t] = t * CAP;
}

// Block-level LDS counting sort of a 4096-edge chunk (512 threads):
//   LDS hist -> block scan -> reserve global runs (1 atomic/bucket, regions
//   are fixed-capacity) -> LDS scatter (records + bucket-id bytes) ->
//   coalesced flush with O(1) bucket lookup. Records: (src<<10)|local_dst.
__global__ __launch_bounds__(BIN_TH) void bin_kernel(const int* __restrict__ src,
                                                     const int* __restrict__ dst,
                                                     int* __restrict__ bucket_cur,
                                                     unsigned int* __restrict__ binned,
                                                     int E, int NB) {
    __shared__ int h[MAX_NB];          // hist, then reused as scatter cursor
    __shared__ int scl[MAX_NB + 1];    // block-local exclusive offsets
    __shared__ int base[MAX_NB];       // global run bases
    __shared__ int sscan[256];
    __shared__ unsigned int stage[BIN_CHUNK];   // 16 KB
    __shared__ unsigned char bkt8[BIN_CHUNK];   // 4 KB bucket ids
    int cbeg = blockIdx.x * BIN_CHUNK;
    int cend = min(cbeg + BIN_CHUNK, E);
    int chunk_n = cend - cbeg;
    int tid = threadIdx.x;

    for (int t = tid; t < NB; t += BIN_TH) h[t] = 0;
    __syncthreads();
    int myd[EPT];
#pragma unroll
    for (int j = 0; j < EPT; j++) {
        int e = cbeg + tid + j * BIN_TH;
        if (e < cend) {
            myd[j] = dst[e];
            atomicAdd(&h[myd[j] >> 10], 1);
        }
    }
    __syncthreads();
    // exclusive scan of h[0..NB) using the first 256 threads (NB <= 256);
    // ALL threads execute the same barrier sequence.
    int v = (tid < NB) ? h[tid] : 0;
    if (tid < 256) sscan[tid] = v;
    __syncthreads();
    for (int off = 1; off < 256; off <<= 1) {
        int t = (tid >= off && tid < 256) ? sscan[tid - off] : 0;
        __syncthreads();
        if (tid < 256) sscan[tid] += t;
        __syncthreads();
    }
    if (tid < NB) {
        scl[tid] = sscan[tid] - v;
        base[tid] = v ? atomicAdd(&bucket_cur[tid], v) : 0;
    }
    if (tid == 0) scl[NB] = chunk_n;
    __syncthreads();
    for (int t = tid; t < NB; t += BIN_TH) h[t] = 0;  // reuse as cursor
    __syncthreads();
#pragma unroll
    for (int j = 0; j < EPT; j++) {
        int e = cbeg + tid + j * BIN_TH;
        if (e < cend) {
            int d = myd[j];
            int bkt = d >> 10;
            int pos = scl[bkt] + atomicAdd(&h[bkt], 1);
            stage[pos] = ((unsigned)src[e] << 10) | (unsigned)(d & 1023);
            bkt8[pos] = (unsigned char)bkt;
        }
    }
    __syncthreads();
    // coalesced flush: O(1) bucket lookup via bkt8
    for (int k = tid; k < chunk_n; k += BIN_TH) {
        int bkt = bkt8[k];
        binned[base[bkt] + (k - scl[bkt])] = stage[k];
    }
}

// One WG per FULL bucket (1024 nodes, 1024 threads): per-node count + scan
// in LDS, emit rows(int2)/dis, scatter src into LDS colbuf, flush coalesced.
__global__ __launch_bounds__(1024) void csr_bucket_kernel(
    const unsigned int* __restrict__ binned,
    const int* __restrict__ bucket_cur,
    int2* __restrict__ rows, float* __restrict__ dis,
    int* __restrict__ col, int N) {
    __shared__ int cnt[NPB];
    __shared__ int cur[NPB];
    __shared__ int colbuf[MAXB];   // 104 KB
    int b = blockIdx.x;
    int nbase = b << 10;
    int nlocal = min(NPB, N - nbase);
    int beg = b * CAP;
    int bsize = bucket_cur[b] - beg;
    int tid = threadIdx.x;

    cnt[tid] = 0;
    __syncthreads();
    for (int k = tid; k < bsize; k += 1024)
        atomicAdd(&cnt[binned[beg + k] & 1023u], 1);
    __syncthreads();
    int v = cnt[tid];
    cur[tid] = v;
    __syncthreads();
    for (int off = 1; off < 1024; off <<= 1) {
        int t = (tid >= off) ? cur[tid - off] : 0;
        __syncthreads();
        cur[tid] += t;
        __syncthreads();
    }
    int excl = cur[tid] - v;
    if (tid < nlocal) {
        rows[nbase + tid] = make_int2(beg + excl, beg + excl + v);
        dis[nbase + tid] = 1.0f / sqrtf((float)(v + 1));  // +1 self-loop
    }
    __syncthreads();
    cur[tid] = excl;
    __syncthreads();
    if (bsize <= MAXB) {
        for (int k = tid; k < bsize; k += 1024) {
            unsigned rec = binned[beg + k];
            int pos = atomicAdd(&cur[rec & 1023u], 1);
            colbuf[pos] = (int)(rec >> 10);
        }
        __syncthreads();
        for (int k = tid; k < bsize; k += 1024) col[beg + k] = colbuf[k];
    } else {  // cannot trigger with CAP sizing; correctness fallback
        for (int k = tid; k < bsize; k += 1024) {
            unsigned rec = binned[beg + k];
            int pos = atomicAdd(&cur[rec & 1023u], 1);
            col[beg + pos] = (int)(rec >> 10);
        }
    }
}

// PREACT: 0 = raw input (layer 1), 1 = bias + relu, 2 = bias only.
// SPLITIN: input from two chunk arrays of IN/2 each (SoA agg).
template <int IN, int OUT, int C, int PREACT, bool SPLITIN>
__global__ __launch_bounds__(256) void transform_kernel(
    const float* __restrict__ hin0, const float* __restrict__ hin1,
    const float* __restrict__ bias_prev,
    const float* __restrict__ W, const float* __restrict__ dis,
    __half* __restrict__ xls, int N) {
    __shared__ float sW[IN * OUT];
    __shared__ float sB[IN];
    for (int t = threadIdx.x; t < IN * OUT; t += blockDim.x) sW[t] = W[t];
    if (PREACT != 0) {
        for (int t = threadIdx.x; t < IN; t += blockDim.x) sB[t] = bias_prev[t];
    }
    __syncthreads();
    int i = blockIdx.x * blockDim.x + threadIdx.x;
    if (i >= N) return;

    constexpr int CIN = SPLITIN ? IN / 2 : IN;
    float h[IN];
#pragma unroll
    for (int k = 0; k < IN; k++) {
        float v;
        if (SPLITIN)
            v = (k < CIN) ? hin0[(size_t)i * CIN + k]
                          : hin1[(size_t)i * CIN + (k - CIN)];
        else
            v = hin0[(size_t)i * IN + k];
        if (PREACT != 0) {
            v += sB[k];
            if (PREACT == 1) v = fmaxf(v, 0.0f);
        }
        h[k] = v;
    }
    float d = dis[i];
    float o[OUT];
#pragma unroll
    for (int f = 0; f < OUT; f++) {
        float acc = 0.0f;
#pragma unroll
        for (int k = 0; k < IN; k++) acc = fmaf(h[k], sW[k * OUT + f], acc);
        o[f] = acc * d;  // pre-scaled by dis[i]
    }
    constexpr int NCH = OUT / C;
    constexpr int P = C / 2;
    __half2* x2 = (__half2*)xls;
#pragma unroll
    for (int c = 0; c < NCH; c++) {
#pragma unroll
        for (int k = 0; k < P; k++) {
            x2[(size_t)c * N * P + (size_t)i * P + k] =
                __floats2half2_rn(o[c * C + 2 * k], o[c * C + 2 * k + 1]);
        }
    }
}

// Accumulate one source node's C features into acc.
template <int P>
__device__ __forceinline__ void acc_node(const __half2* __restrict__ x2, int c,
                                         float2 (&acc)[P]) {
    __half2 t[P];
#pragma unroll
    for (int k = 0; k < P; k++) t[k] = x2[(size_t)c * P + k];
#pragma unroll
    for (int k = 0; k < P; k++) {
        float2 v = __half22float2(t[k]);
        acc[k].x += v.x;
        acc[k].y += v.y;
    }
}

template <int P>
__device__ __forceinline__ void acc_quad(const __half2* __restrict__ x2, int4 c,
                                         float2 (&acc)[P]) {
    __half2 t[4][P];
#pragma unroll
    for (int k = 0; k < P; k++) t[0][k] = x2[(size_t)c.x * P + k];
#pragma unroll
    for (int k = 0; k < P; k++) t[1][k] = x2[(size_t)c.y * P + k];
#pragma unroll
    for (int k = 0; k < P; k++) t[2][k] = x2[(size_t)c.z * P + k];
#pragma unroll
    for (int k = 0; k < P; k++) t[3][k] = x2[(size_t)c.w * P + k];
#pragma unroll
    for (int k = 0; k < P; k++) {
        float2 a0 = __half22float2(t[0][k]), a1 = __half22float2(t[1][k]);
        float2 a2 = __half22float2(t[2][k]), a3 = __half22float2(t[3][k]);
        acc[k].x += (a0.x + a1.x) + (a2.x + a3.x);
        acc[k].y += (a0.y + a1.y) + (a2.y + a3.y);
    }
}

// Pull gather body: lane-pair per node, 16B-aligned int4 col quads, lane p
// handles quads p, p+2, ..., unrolled x3 (12 table loads in flight).
// Epilogue: SIG=false -> store acc*d to outp (contiguous, stride OST=C);
//           SIG=true  -> store sigmoid(acc*d + bias[coff+f]) (stride OST).
template <int C, bool SIG, int OST>
__device__ __forceinline__ void gather_body(
    int i, int p, const int2* __restrict__ rows, const int* __restrict__ col,
    const float* __restrict__ dis, const __half2* __restrict__ x2,
    float* __restrict__ outp, const float* __restrict__ bias, int coff) {
    constexpr int P = C / 2;
    float2 acc[P];
#pragma unroll
    for (int k = 0; k < P; k++) {
        if (p == 0) acc[k] = __half22float2(x2[(size_t)i * P + k]);  // self-loop
        else acc[k] = make_float2(0.0f, 0.0f);
    }
    int2 r = rows[i];
    int beg = r.x;
    int end = r.y;
    int nedge = end - beg;
    // scalar prologue to 16B alignment (lane p takes alternating edges)
    int pre = (4 - (beg & 3)) & 3;
    if (pre > nedge) pre = nedge;
    for (int j = p; j < pre; j += 2) acc_node<P>(x2, col[beg + j], acc);
    int abeg = beg + pre;
    int nq = (end - abeg) >> 2;  // full aligned quads
    int q = p;
    // unroll x3: three quads (12 edges / 12 table loads) in flight per lane
    for (; q + 4 < nq; q += 6) {
        int4 ca = *reinterpret_cast<const int4*>(col + abeg + 4 * q);
        int4 cb = *reinterpret_cast<const int4*>(col + abeg + 4 * (q + 2));
        int4 cc = *reinterpret_cast<const int4*>(col + abeg + 4 * (q + 4));
        acc_quad<P>(x2, ca, acc);
        acc_quad<P>(x2, cb, acc);
        acc_quad<P>(x2, cc, acc);
    }
    for (; q < nq; q += 2) {  // leftover quads for this lane (up to 2)
        int4 ca = *reinterpret_cast<const int4*>(col + abeg + 4 * q);
        acc_quad<P>(x2, ca, acc);
    }
    // scalar tail (lane p takes alternating edges)
    int tbeg = abeg + 4 * nq;
    for (int j = tbeg + p; j < end; j += 2) acc_node<P>(x2, col[j], acc);
    // combine pair partials (both lanes end with the full sum)
#pragma unroll
    for (int k = 0; k < P; k++) {
        acc[k].x += __shfl_xor(acc[k].x, 1);
        acc[k].y += __shfl_xor(acc[k].y, 1);
    }
    float d = dis[i];
    float* op = outp + (size_t)i * OST + coff;
#pragma unroll
    for (int k = 0; k < P; k++) {
        if ((k & 1) == p) {
            float vx = acc[k].x * d;
            float vy = acc[k].y * d;
            if (SIG) {
                vx = 1.0f / (1.0f + expf(-(vx + bias[coff + 2 * k])));
                vy = 1.0f / (1.0f + expf(-(vy + bias[coff + 2 * k + 1])));
            }
            *reinterpret_cast<float2*>(op + 2 * k) = make_float2(vx, vy);
        }
    }
}

// Single-chunk gather (layer 2).
template <int C>
__global__ __launch_bounds__(256) void gather_kernel(
    const int2* __restrict__ rows, const int* __restrict__ col,
    const float* __restrict__ dis, const __half* __restrict__ xls,
    float* __restrict__ aggc, int N) {
    int tid = blockIdx.x * blockDim.x + threadIdx.x;
    int i = tid >> 1;
    int p = tid & 1;
    if (i >= N) return;
    gather_body<C, false, C>(i, p, rows, col, dis, (const __half2*)xls, aggc,
                             nullptr, 0);
}

// Merged two-chunk gather: chunk = (blockIdx&7)>=4. With round-robin
// block->XCD dispatch each XCD's L2 caches only one 3.2 MB chunk table;
// coverage (and thus correctness) does not depend on the mapping.
template <int C>
__global__ __launch_bounds__(256) void gather2_kernel(
    const int2* __restrict__ rows, const int* __restrict__ col,
    const float* __restrict__ dis, const __half* __restrict__ x0,
    const __half* __restrict__ x1, float* __restrict__ agg0,
    float* __restrict__ agg1, int N) {
    int grp = blockIdx.x >> 3;
    int sub = blockIdx.x & 7;
    int chunk = sub >> 2;
    int range = (grp << 2) + (sub & 3);
    int t2 = range * 256 + (int)threadIdx.x;
    int i = t2 >> 1;
    int p = t2 & 1;
    if (i >= N) return;
    const __half2* x2 = (const __half2*)(chunk ? x1 : x0);
    float* aggc = chunk ? agg1 : agg0;
    gather_body<C, false, C>(i, p, rows, col, dis, x2, aggc, nullptr, 0);
}

// Layer-4 merged gather with fused bias+sigmoid epilogue -> out (stride 12).
__global__ __launch_bounds__(256) void gather2_sig_kernel(
    const int2* __restrict__ rows, const int* __restrict__ col,
    const float* __restrict__ dis, const __half* __restrict__ x0,
    const __half* __restrict__ x1, const float* __restrict__ bias,
    float* __restrict__ out, int N) {
    int grp = blockIdx.x >> 3;
    int sub = blockIdx.x & 7;
    int chunk = sub >> 2;
    int range = (grp << 2) + (sub & 3);
    int t2 = range * 256 + (int)threadIdx.x;
    int i = t2 >> 1;
    int p = t2 & 1;
    if (i >= N) return;
    const __half2* x2 = (const __half2*)(chunk ? x1 : x0);
    gather_body<6, true, 12>(i, p, rows, col, dis, x2, out, bias, chunk ? 6 : 0);
}

static inline size_t align_up(size_t v, size_t a) { return (v + a - 1) & ~(a - 1); }

extern "C" void kernel_launch(void* const* d_in, const int* in_sizes, int n_in,
                              void* d_out, int out_size, void* d_ws, size_t ws_size,
                              hipStream_t stream) {
    const float* x  = (const float*)d_in[0];
    const int*   ei = (const int*)d_in[1];
    const float* W1 = (const float*)d_in[2];
    const float* b1 = (const float*)d_in[3];
    const float* W2 = (const float*)d_in[4];
    const float* b2 = (const float*)d_in[5];
    const float* W3 = (const float*)d_in[6];
    const float* b3 = (const float*)d_in[7];
    const float* W4 = (const float*)d_in[8];
    const float* b4 = (const float*)d_in[9];
    float* out = (float*)d_out;

    const int N = in_sizes[0] / 12;
    const int E = in_sizes[1] / 2;
    const int* src = ei;       // edge_index[0]
    const int* dst = ei + E;   // edge_index[1]
    const int NB = (N + NPB - 1) / NPB;  // 196

    // Workspace carve-up (~77 MB)
    char* ws = (char*)d_ws;
    size_t off = 0;
    int* bucket_cur = (int*)(ws + off);   off = align_up(off + (size_t)NB * 4, 256);
    int2* rows = (int2*)(ws + off);       off = align_up(off + (size_t)N * 8, 256);
    float* dis = (float*)(ws + off);      off = align_up(off + (size_t)N * 4, 256);
    unsigned int* binned = (unsigned int*)(ws + off);
    off = align_up(off + ((size_t)NB * CAP + 4096) * 4, 256);
    int* col = (int*)(ws + off);          off = align_up(off + ((size_t)NB * CAP + 4096) * 4, 256);
    __half* xls = (__half*)(ws + off);    off = align_up(off + (size_t)N * 16 * 2, 256);
    float* aggA = (float*)(ws + off);     off = align_up(off + (size_t)N * 16 * 4, 256);
    float* aggB = (float*)(ws + off);     off = align_up(off + (size_t)N * 16 * 4, 256);
    (void)ws_size; (void)n_in; (void)out_size;

    const int B = 256;
    auto blocks = [&](long long n) { return (int)((n + B - 1) / B); };
    int nb2 = blocks(2LL * N);          // ranges for merged gather
    nb2 = (nb2 + 3) & ~3;               // multiple of 4
    const int G2 = nb2 * 2;             // merged-gather grid (mult of 8)

    // --- CSR build: fixed-capacity bucketed counting sort ----------------
    init_cur_kernel<<<1, 256, 0, stream>>>(bucket_cur, NB);
    bin_kernel<<<(E + BIN_CHUNK - 1) / BIN_CHUNK, BIN_TH, 0, stream>>>(src, dst, bucket_cur, binned, E, NB);
    csr_bucket_kernel<<<NB, 1024, 0, stream>>>(binned, bucket_cur, rows, dis, col, N);

    // xls chunk-table bases (half units): chunk c of size C lives at c*N*C
    __half* x_c0 = xls;
    __half* x_c8 = xls + (size_t)N * 8;  // second chunk for C=8 layers
    __half* x_c6 = xls + (size_t)N * 6;  // second chunk for C=6 layer
    // SoA agg chunk bases
    float* aggA0 = aggA;
    float* aggA1 = aggA + (size_t)N * 8;
    float* aggB0 = aggB;

    // --- Layer 1: x(12) @ W1 -> 16 (chunks 2x8, merged gather) -----------
    transform_kernel<12, 16, 8, 0, false><<<blocks(N), B, 0, stream>>>(
        x, nullptr, nullptr, W1, dis, xls, N);
    gather2_kernel<8><<<G2, B, 0, stream>>>(rows, col, dis, x_c0, x_c8, aggA0, aggA1, N);

    // --- Layer 2: relu(aggA + b1)(16) @ W2 -> 8 (1x8) --------------------
    transform_kernel<16, 8, 8, 1, true><<<blocks(N), B, 0, stream>>>(
        aggA0, aggA1, b1, W2, dis, xls, N);
    gather_kernel<8><<<blocks(2LL * N), B, 0, stream>>>(rows, col, dis, x_c0, aggB0, N);

    // --- Layer 3: (aggB + b2)(8) @ W3 -> 16 (2x8 merged, no relu) --------
    transform_kernel<8, 16, 8, 2, false><<<blocks(N), B, 0, stream>>>(
        aggB0, nullptr, b2, W3, dis, xls, N);
    gather2_kernel<8><<<G2, B, 0, stream>>>(rows, col, dis, x_c0, x_c8, aggA0, aggA1, N);

    // --- Layer 4: relu(aggA + b3)(16) @ W4 -> 12 (2x6 merged,
    //     fused bias+sigmoid epilogue straight to out) --------------------
    transform_kernel<16, 12, 6, 1, true><<<blocks(N), B, 0, stream>>>(
        aggA0, aggA1, b3, W4, dis, xls, N);
    gather2_sig_kernel<<<G2, B, 0, stream>>>(rows, col, dis, x_c0, x_c6, b4, out, N);
}

// Round 15
// 404.744 us; speedup vs baseline: 1.0693x; 1.0094x over previous
//
#include <hip/hip_runtime.h>
#include <hip/hip_fp16.h>
#include <math.h>

// ---------------------------------------------------------------------------
// GCN autoencoder: 4 layers (12->16->8->16->12), N=200K nodes, E=5M edges.
//
// Round 15 (on R14's 408 us): two fusions, math unchanged.
//  * transform1 fused into csr_bucket tail (per-thread node already has dis
//    in-register) -> kernel + gap gone.
//  * transform3 fused into the layer-2 gather epilogue (layer-2 agg is one
//    8-feature chunk, so the lane-pair holds the full transform3 input) ->
//    kernel + gap + 12.8 MB aggB round trip gone. Layer-3 tables written to
//    a separate buffer (old aggB space) to avoid racing the layer-2 table.
// Gather structure stays at the R12/R14 sweet spot: unroll x3, ~35% occ.
// ---------------------------------------------------------------------------

#define NPB 1024               // nodes per bucket; bucket id = dst >> 10
#define MAX_NB 256             // supports N <= 262144
#define CAP 26496              // bucket region capacity (mean 25510 + ~6s)
#define BIN_CHUNK 4096         // edges per workgroup in bin_kernel
#define BIN_TH 512             // threads per workgroup in bin_kernel
#define EPT (BIN_CHUNK / BIN_TH)  // edges per thread (8)
#define MAXB CAP               // LDS col staging capacity (full bucket)

__global__ void init_cur_kernel(int* __restrict__ bucket_cur, int NB) {
    int t = blockIdx.x * blockDim.x + threadIdx.x;
    if (t < NB) bucket_cur[t] = t * CAP;
}

// Block-level LDS counting sort of a 4096-edge chunk (512 threads):
//   LDS hist -> block scan -> reserve global runs (1 atomic/bucket, regions
//   are fixed-capacity) -> LDS scatter (records + bucket-id bytes) ->
//   coalesced flush with O(1) bucket lookup. Records: (src<<10)|local_dst.
__global__ __launch_bounds__(BIN_TH) void bin_kernel(const int* __restrict__ src,
                                                     const int* __restrict__ dst,
                                                     int* __restrict__ bucket_cur,
                                                     unsigned int* __restrict__ binned,
                                                     int E, int NB) {
    __shared__ int h[MAX_NB];          // hist, then reused as scatter cursor
    __shared__ int scl[MAX_NB + 1];    // block-local exclusive offsets
    __shared__ int base[MAX_NB];       // global run bases
    __shared__ int sscan[256];
    __shared__ unsigned int stage[BIN_CHUNK];   // 16 KB
    __shared__ unsigned char bkt8[BIN_CHUNK];   // 4 KB bucket ids
    int cbeg = blockIdx.x * BIN_CHUNK;
    int cend = min(cbeg + BIN_CHUNK, E);
    int chunk_n = cend - cbeg;
    int tid = threadIdx.x;

    for (int t = tid; t < NB; t += BIN_TH) h[t] = 0;
    __syncthreads();
    int myd[EPT];
#pragma unroll
    for (int j = 0; j < EPT; j++) {
        int e = cbeg + tid + j * BIN_TH;
        if (e < cend) {
            myd[j] = dst[e];
            atomicAdd(&h[myd[j] >> 10], 1);
        }
    }
    __syncthreads();
    // exclusive scan of h[0..NB) using the first 256 threads (NB <= 256);
    // ALL threads execute the same barrier sequence.
    int v = (tid < NB) ? h[tid] : 0;
    if (tid < 256) sscan[tid] = v;
    __syncthreads();
    for (int off = 1; off < 256; off <<= 1) {
        int t = (tid >= off && tid < 256) ? sscan[tid - off] : 0;
        __syncthreads();
        if (tid < 256) sscan[tid] += t;
        __syncthreads();
    }
    if (tid < NB) {
        scl[tid] = sscan[tid] - v;
        base[tid] = v ? atomicAdd(&bucket_cur[tid], v) : 0;
    }
    if (tid == 0) scl[NB] = chunk_n;
    __syncthreads();
    for (int t = tid; t < NB; t += BIN_TH) h[t] = 0;  // reuse as cursor
    __syncthreads();
#pragma unroll
    for (int j = 0; j < EPT; j++) {
        int e = cbeg + tid + j * BIN_TH;
        if (e < cend) {
            int d = myd[j];
            int bkt = d >> 10;
            int pos = scl[bkt] + atomicAdd(&h[bkt], 1);
            stage[pos] = ((unsigned)src[e] << 10) | (unsigned)(d & 1023);
            bkt8[pos] = (unsigned char)bkt;
        }
    }
    __syncthreads();
    // coalesced flush: O(1) bucket lookup via bkt8
    for (int k = tid; k < chunk_n; k += BIN_TH) {
        int bkt = bkt8[k];
        binned[base[bkt] + (k - scl[bkt])] = stage[k];
    }
}

// One WG per FULL bucket (1024 nodes, 1024 threads): per-node count + scan
// in LDS, emit rows(int2)/dis, scatter src into LDS colbuf, flush coalesced.
// FUSED transform1 tail: xls1 = (x @ W1) * dis, written as 2x8 fp16 chunks.
__global__ __launch_bounds__(1024) void csr_bucket_t1_kernel(
    const unsigned int* __restrict__ binned,
    const int* __restrict__ bucket_cur,
    int2* __restrict__ rows, float* __restrict__ dis,
    int* __restrict__ col,
    const float* __restrict__ x, const float* __restrict__ W1,
    __half* __restrict__ xls, int N) {
    __shared__ int cnt[NPB];
    __shared__ int cur[NPB];
    __shared__ int colbuf[MAXB];   // 104 KB
    __shared__ float sW[12 * 16];
    int b = blockIdx.x;
    int nbase = b << 10;
    int nlocal = min(NPB, N - nbase);
    int beg = b * CAP;
    int bsize = bucket_cur[b] - beg;
    int tid = threadIdx.x;

    if (tid < 192) sW[tid] = W1[tid];
    cnt[tid] = 0;
    __syncthreads();
    for (int k = tid; k < bsize; k += 1024)
        atomicAdd(&cnt[binned[beg + k] & 1023u], 1);
    __syncthreads();
    int v = cnt[tid];
    cur[tid] = v;
    __syncthreads();
    for (int off = 1; off < 1024; off <<= 1) {
        int t = (tid >= off) ? cur[tid - off] : 0;
        __syncthreads();
        cur[tid] += t;
        __syncthreads();
    }
    int excl = cur[tid] - v;
    float d = 1.0f / sqrtf((float)(v + 1));  // +1 self-loop
    if (tid < nlocal) {
        rows[nbase + tid] = make_int2(beg + excl, beg + excl + v);
        dis[nbase + tid] = d;
    }
    __syncthreads();
    cur[tid] = excl;
    __syncthreads();
    if (bsize <= MAXB) {
        for (int k = tid; k < bsize; k += 1024) {
            unsigned rec = binned[beg + k];
            int pos = atomicAdd(&cur[rec & 1023u], 1);
            colbuf[pos] = (int)(rec >> 10);
        }
        __syncthreads();
        for (int k = tid; k < bsize; k += 1024) col[beg + k] = colbuf[k];
    } else {  // cannot trigger with CAP sizing; correctness fallback
        for (int k = tid; k < bsize; k += 1024) {
            unsigned rec = binned[beg + k];
            int pos = atomicAdd(&cur[rec & 1023u], 1);
            col[beg + pos] = (int)(rec >> 10);
        }
    }
    // ---- fused transform1: xls = (x @ W1) * dis, chunks 2x8 -------------
    if (tid < nlocal) {
        int i = nbase + tid;
        float h[12];
#pragma unroll
        for (int k = 0; k < 12; k++) h[k] = x[(size_t)i * 12 + k];
        float o[16];
#pragma unroll
        for (int f = 0; f < 16; f++) {
            float acc = 0.0f;
#pragma unroll
            for (int k = 0; k < 12; k++) acc = fmaf(h[k], sW[k * 16 + f], acc);
            o[f] = acc * d;
        }
        __half2* x2 = (__half2*)xls;
#pragma unroll
        for (int c = 0; c < 2; c++) {
#pragma unroll
            for (int k = 0; k < 4; k++) {
                x2[(size_t)c * N * 4 + (size_t)i * 4 + k] =
                    __floats2half2_rn(o[c * 8 + 2 * k], o[c * 8 + 2 * k + 1]);
            }
        }
    }
}

// PREACT: 0 = raw input, 1 = bias + relu, 2 = bias only.
// SPLITIN: input from two chunk arrays of IN/2 each (SoA agg).
template <int IN, int OUT, int C, int PREACT, bool SPLITIN>
__global__ __launch_bounds__(256) void transform_kernel(
    const float* __restrict__ hin0, const float* __restrict__ hin1,
    const float* __restrict__ bias_prev,
    const float* __restrict__ W, const float* __restrict__ dis,
    __half* __restrict__ xls, int N) {
    __shared__ float sW[IN * OUT];
    __shared__ float sB[IN];
    for (int t = threadIdx.x; t < IN * OUT; t += blockDim.x) sW[t] = W[t];
    if (PREACT != 0) {
        for (int t = threadIdx.x; t < IN; t += blockDim.x) sB[t] = bias_prev[t];
    }
    __syncthreads();
    int i = blockIdx.x * blockDim.x + threadIdx.x;
    if (i >= N) return;

    constexpr int CIN = SPLITIN ? IN / 2 : IN;
    float h[IN];
#pragma unroll
    for (int k = 0; k < IN; k++) {
        float v;
        if (SPLITIN)
            v = (k < CIN) ? hin0[(size_t)i * CIN + k]
                          : hin1[(size_t)i * CIN + (k - CIN)];
        else
            v = hin0[(size_t)i * IN + k];
        if (PREACT != 0) {
            v += sB[k];
            if (PREACT == 1) v = fmaxf(v, 0.0f);
        }
        h[k] = v;
    }
    float d = dis[i];
    float o[OUT];
#pragma unroll
    for (int f = 0; f < OUT; f++) {
        float acc = 0.0f;
#pragma unroll
        for (int k = 0; k < IN; k++) acc = fmaf(h[k], sW[k * OUT + f], acc);
        o[f] = acc * d;  // pre-scaled by dis[i]
    }
    constexpr int NCH = OUT / C;
    constexpr int P = C / 2;
    __half2* x2 = (__half2*)xls;
#pragma unroll
    for (int c = 0; c < NCH; c++) {
#pragma unroll
        for (int k = 0; k < P; k++) {
            x2[(size_t)c * N * P + (size_t)i * P + k] =
                __floats2half2_rn(o[c * C + 2 * k], o[c * C + 2 * k + 1]);
        }
    }
}

// Accumulate one source node's C features into acc.
template <int P>
__device__ __forceinline__ void acc_node(const __half2* __restrict__ x2, int c,
                                         float2 (&acc)[P]) {
    __half2 t[P];
#pragma unroll
    for (int k = 0; k < P; k++) t[k] = x2[(size_t)c * P + k];
#pragma unroll
    for (int k = 0; k < P; k++) {
        float2 v = __half22float2(t[k]);
        acc[k].x += v.x;
        acc[k].y += v.y;
    }
}

template <int P>
__device__ __forceinline__ void acc_quad(const __half2* __restrict__ x2, int4 c,
                                         float2 (&acc)[P]) {
    __half2 t[4][P];
#pragma unroll
    for (int k = 0; k < P; k++) t[0][k] = x2[(size_t)c.x * P + k];
#pragma unroll
    for (int k = 0; k < P; k++) t[1][k] = x2[(size_t)c.y * P + k];
#pragma unroll
    for (int k = 0; k < P; k++) t[2][k] = x2[(size_t)c.z * P + k];
#pragma unroll
    for (int k = 0; k < P; k++) t[3][k] = x2[(size_t)c.w * P + k];
#pragma unroll
    for (int k = 0; k < P; k++) {
        float2 a0 = __half22float2(t[0][k]), a1 = __half22float2(t[1][k]);
        float2 a2 = __half22float2(t[2][k]), a3 = __half22float2(t[3][k]);
        acc[k].x += (a0.x + a1.x) + (a2.x + a3.x);
        acc[k].y += (a0.y + a1.y) + (a2.y + a3.y);
    }
}

// Core gather accumulation (no epilogue): lane-pair per node, 16B-aligned
// int4 col quads, unroll x3 (12 table loads in flight), shfl-combined.
// After return, BOTH lanes hold the complete aggregated sum in acc.
template <int C>
__device__ __forceinline__ void gather_acc(
    int i, int p, const int2* __restrict__ rows, const int* __restrict__ col,
    const __half2* __restrict__ x2, float2 (&acc)[C / 2]) {
    constexpr int P = C / 2;
#pragma unroll
    for (int k = 0; k < P; k++) {
        if (p == 0) acc[k] = __half22float2(x2[(size_t)i * P + k]);  // self-loop
        else acc[k] = make_float2(0.0f, 0.0f);
    }
    int2 r = rows[i];
    int beg = r.x;
    int end = r.y;
    int nedge = end - beg;
    // scalar prologue to 16B alignment (lane p takes alternating edges)
    int pre = (4 - (beg & 3)) & 3;
    if (pre > nedge) pre = nedge;
    for (int j = p; j < pre; j += 2) acc_node<P>(x2, col[beg + j], acc);
    int abeg = beg + pre;
    int nq = (end - abeg) >> 2;  // full aligned quads
    int q = p;
    // unroll x3: three quads (12 edges / 12 table loads) in flight per lane
    for (; q + 4 < nq; q += 6) {
        int4 ca = *reinterpret_cast<const int4*>(col + abeg + 4 * q);
        int4 cb = *reinterpret_cast<const int4*>(col + abeg + 4 * (q + 2));
        int4 cc = *reinterpret_cast<const int4*>(col + abeg + 4 * (q + 4));
        acc_quad<P>(x2, ca, acc);
        acc_quad<P>(x2, cb, acc);
        acc_quad<P>(x2, cc, acc);
    }
    for (; q < nq; q += 2) {  // leftover quads for this lane (up to 2)
        int4 ca = *reinterpret_cast<const int4*>(col + abeg + 4 * q);
        acc_quad<P>(x2, ca, acc);
    }
    // scalar tail (lane p takes alternating edges)
    int tbeg = abeg + 4 * nq;
    for (int j = tbeg + p; j < end; j += 2) acc_node<P>(x2, col[j], acc);
    // combine pair partials (both lanes end with the full sum)
#pragma unroll
    for (int k = 0; k < P; k++) {
        acc[k].x += __shfl_xor(acc[k].x, 1);
        acc[k].y += __shfl_xor(acc[k].y, 1);
    }
}

// Merged two-chunk gather: chunk = (blockIdx&7)>=4. With round-robin
// block->XCD dispatch each XCD's L2 caches only one 3.2 MB chunk table;
// coverage (and thus correctness) does not depend on the mapping.
template <int C>
__global__ __launch_bounds__(256) void gather2_kernel(
    const int2* __restrict__ rows, const int* __restrict__ col,
    const float* __restrict__ dis, const __half* __restrict__ x0,
    const __half* __restrict__ x1, float* __restrict__ agg0,
    float* __restrict__ agg1, int N) {
    constexpr int P = C / 2;
    int grp = blockIdx.x >> 3;
    int sub = blockIdx.x & 7;
    int chunk = sub >> 2;
    int range = (grp << 2) + (sub & 3);
    int t2 = range * 256 + (int)threadIdx.x;
    int i = t2 >> 1;
    int p = t2 & 1;
    if (i >= N) return;
    const __half2* x2 = (const __half2*)(chunk ? x1 : x0);
    float* aggc = chunk ? agg1 : agg0;
    float2 acc[P];
    gather_acc<C>(i, p, rows, col, x2, acc);
    float d = dis[i];
    float2* ap = (float2*)(aggc + (size_t)i * C);
#pragma unroll
    for (int k = 0; k < P; k++) {
        if ((k & 1) == p) ap[k] = make_float2(acc[k].x * d, acc[k].y * d);
    }
}

// Layer-2 gather (C=8, single chunk) with FUSED transform3:
//   v_k = acc_k * dis + b2[k]  (no relu after layer 2)
//   o_f = (sum_k v_k * W3[k][f]) * dis   -> layer-3 tables (2x8) in xout.
// Lane p of the pair computes features [p*8, p*8+8) and writes chunk p.
__global__ __launch_bounds__(256) void gather_t3_kernel(
    const int2* __restrict__ rows, const int* __restrict__ col,
    const float* __restrict__ dis, const __half* __restrict__ xls,
    const float* __restrict__ b2, const float* __restrict__ W3,
    __half* __restrict__ xout, int N) {
    __shared__ float sW[8 * 16];
    __shared__ float sB[8];
    if (threadIdx.x < 128) sW[threadIdx.x] = W3[threadIdx.x];
    if (threadIdx.x < 8) sB[threadIdx.x] = b2[threadIdx.x];
    __syncthreads();
    int tid = blockIdx.x * blockDim.x + threadIdx.x;
    int i = tid >> 1;
    int p = tid & 1;
    if (i >= N) return;
    float2 acc[4];
    gather_acc<8>(i, p, rows, col, (const __half2*)xls, acc);
    float d = dis[i];
    float v[8];
#pragma unroll
    for (int k = 0; k < 4; k++) {
        v[2 * k] = acc[k].x * d + sB[2 * k];
        v[2 * k + 1] = acc[k].y * d + sB[2 * k + 1];
    }
    // lane p computes output features [p*8, p*8+8) = chunk p
    float o[8];
#pragma unroll
    for (int f = 0; f < 8; f++) {
        float a = 0.0f;
#pragma unroll
        for (int k = 0; k < 8; k++) a = fmaf(v[k], sW[k * 16 + p * 8 + f], a);
        o[f] = a * d;
    }
    __half2* x2o = (__half2*)xout;
#pragma unroll
    for (int k = 0; k < 4; k++) {
        x2o[(size_t)p * N * 4 + (size_t)i * 4 + k] =
            __floats2half2_rn(o[2 * k], o[2 * k + 1]);
    }
}

// Layer-4 merged gather with fused bias+sigmoid epilogue -> out (stride 12).
__global__ __launch_bounds__(256) void gather2_sig_kernel(
    const int2* __restrict__ rows, const int* __restrict__ col,
    const float* __restrict__ dis, const __half* __restrict__ x0,
    const __half* __restrict__ x1, const float* __restrict__ bias,
    float* __restrict__ out, int N) {
    int grp = blockIdx.x >> 3;
    int sub = blockIdx.x & 7;
    int chunk = sub >> 2;
    int range = (grp << 2) + (sub & 3);
    int t2 = range * 256 + (int)threadIdx.x;
    int i = t2 >> 1;
    int p = t2 & 1;
    if (i >= N) return;
    const __half2* x2 = (const __half2*)(chunk ? x1 : x0);
    int coff = chunk ? 6 : 0;
    float2 acc[3];
    gather_acc<6>(i, p, rows, col, x2, acc);
    float d = dis[i];
    float* op = out + (size_t)i * 12 + coff;
#pragma unroll
    for (int k = 0; k < 3; k++) {
        if ((k & 1) == p) {
            float vx = 1.0f / (1.0f + expf(-(acc[k].x * d + bias[coff + 2 * k])));
            float vy = 1.0f / (1.0f + expf(-(acc[k].y * d + bias[coff + 2 * k + 1])));
            *reinterpret_cast<float2*>(op + 2 * k) = make_float2(vx, vy);
        }
    }
}

static inline size_t align_up(size_t v, size_t a) { return (v + a - 1) & ~(a - 1); }

extern "C" void kernel_launch(void* const* d_in, const int* in_sizes, int n_in,
                              void* d_out, int out_size, void* d_ws, size_t ws_size,
                              hipStream_t stream) {
    const float* x  = (const float*)d_in[0];
    const int*   ei = (const int*)d_in[1];
    const float* W1 = (const float*)d_in[2];
    const float* b1 = (const float*)d_in[3];
    const float* W2 = (const float*)d_in[4];
    const float* b2 = (const float*)d_in[5];
    const float* W3 = (const float*)d_in[6];
    const float* b3 = (const float*)d_in[7];
    const float* W4 = (const float*)d_in[8];
    const float* b4 = (const float*)d_in[9];
    float* out = (float*)d_out;

    const int N = in_sizes[0] / 12;
    const int E = in_sizes[1] / 2;
    const int* src = ei;       // edge_index[0]
    const int* dst = ei + E;   // edge_index[1]
    const int NB = (N + NPB - 1) / NPB;  // 196

    // Workspace carve-up (~71 MB)
    char* ws = (char*)d_ws;
    size_t off = 0;
    int* bucket_cur = (int*)(ws + off);   off = align_up(off + (size_t)NB * 4, 256);
    int2* rows = (int2*)(ws + off);       off = align_up(off + (size_t)N * 8, 256);
    float* dis = (float*)(ws + off);      off = align_up(off + (size_t)N * 4, 256);
    unsigned int* binned = (unsigned int*)(ws + off);
    off = align_up(off + ((size_t)NB * CAP + 4096) * 4, 256);
    int* col = (int*)(ws + off);          off = align_up(off + ((size_t)NB * CAP + 4096) * 4, 256);
    __half* xls = (__half*)(ws + off);    off = align_up(off + (size_t)N * 16 * 2, 256);
    __half* xls2 = (__half*)(ws + off);   off = align_up(off + (size_t)N * 16 * 2, 256);
    float* aggA = (float*)(ws + off);     off = align_up(off + (size_t)N * 16 * 4, 256);
    (void)ws_size; (void)n_in; (void)out_size;

    const int B = 256;
    auto blocks = [&](long long n) { return (int)((n + B - 1) / B); };
    int nb2 = blocks(2LL * N);          // ranges for merged gather
    nb2 = (nb2 + 3) & ~3;               // multiple of 4
    const int G2 = nb2 * 2;             // merged-gather grid (mult of 8)

    // --- CSR build + fused transform1 ------------------------------------
    init_cur_kernel<<<1, 256, 0, stream>>>(bucket_cur, NB);
    bin_kernel<<<(E + BIN_CHUNK - 1) / BIN_CHUNK, BIN_TH, 0, stream>>>(src, dst, bucket_cur, binned, E, NB);
    csr_bucket_t1_kernel<<<NB, 1024, 0, stream>>>(binned, bucket_cur, rows, dis, col,
                                                  x, W1, xls, N);

    // xls chunk-table bases (half units)
    __half* x_c0 = xls;
    __half* x_c8 = xls + (size_t)N * 8;   // second chunk for C=8 layers
    __half* x_c6 = xls + (size_t)N * 6;   // second chunk for C=6 layer
    __half* x2_c0 = xls2;                 // layer-3 tables (separate buffer)
    __half* x2_c8 = xls2 + (size_t)N * 8;
    // SoA agg chunk bases
    float* aggA0 = aggA;
    float* aggA1 = aggA + (size_t)N * 8;

    // --- Layer 1: gather (chunks 2x8, merged) -> aggA --------------------
    gather2_kernel<8><<<G2, B, 0, stream>>>(rows, col, dis, x_c0, x_c8, aggA0, aggA1, N);

    // --- Layer 2 transform: relu(aggA + b1)(16) @ W2 -> 8 (1x8) ----------
    transform_kernel<16, 8, 8, 1, true><<<blocks(N), B, 0, stream>>>(
        aggA0, aggA1, b1, W2, dis, xls, N);

    // --- Layer 2 gather + FUSED transform3 -> layer-3 tables (xls2) ------
    gather_t3_kernel<<<blocks(2LL * N), B, 0, stream>>>(rows, col, dis, x_c0,
                                                        b2, W3, xls2, N);

    // --- Layer 3 gather (chunks 2x8, merged) -> aggA ----------------------
    gather2_kernel<8><<<G2, B, 0, stream>>>(rows, col, dis, x2_c0, x2_c8, aggA0, aggA1, N);

    // --- Layer 4 transform: relu(aggA + b3)(16) @ W4 -> 12 (chunks 2x6) --
    transform_kernel<16, 12, 6, 1, true><<<blocks(N), B, 0, stream>>>(
        aggA0, aggA1, b3, W4, dis, xls, N);

    // --- Layer 4 gather, fused bias+sigmoid -> out ------------------------
    gather2_sig_kernel<<<G2, B, 0, stream>>>(rows, col, dis, x_c0, x_c6, b4, out, N);
}